// Round 9
// baseline (88.205 us; speedup 1.0000x reference)
//
#include <hip/hip_runtime.h>
#include <hip/hip_bf16.h>
#include <stdint.h>
#include <stddef.h>

// DecorrLoss: grad = 0.5*mean_C(offdiag) + 0.5*diag(mean(x^2)-1), corr_loss, whit_loss
// x: f32 [8,4096,1024] -> [M=32768][D=1024]
//   pass1: f32 -> fp8 e4m3 (HW cvt_pk) transposed XT [D][M]; thread = 4 rows x 16
//          cols (16 indep float4 loads), per-thread stats + 4-lane shfl reduce,
//          4x4 register byte transpose, LDS [64][68] u32, 64B/thread store.
//   gemm : C = XT*XT^T via MX-scaled fp8 MFMA 16x16x128 (unit scales), 36 upper-
//          triangle 128x128 tiles, split-K S=32, XCD-chunked, BK=128, 2-phase
//          dbuf LDS, slot^row swizzle via pre-swizzled global src. bf16-packed C.
//   epi  : FUSED: sum S partials -> upper write (+diag-0.5 fixup) + LDS-transposed
//          mirror write of the lower block. No csum intermediate.
//   fin1/fin2: deterministic scalar losses (f32 path, unaffected by fp8)

#define D_DIM 1024
#define M_ROWS 32768
#define BK 128
#define NKBS (M_ROWS / BK)         // 256 K-blocks of 128
#define NTILES 36                  // 8*9/2 triangle tiles
#define TILE_ELEMS 16384           // 128*128
#define CP_U32 8192                // u32 per packed tile (128*128/2)

typedef __attribute__((ext_vector_type(4))) float f32x4;
typedef __attribute__((ext_vector_type(4))) int i32x4;
typedef __attribute__((ext_vector_type(8))) int i32x8;

__device__ inline unsigned short f2bf(float f) {
  unsigned int b = __float_as_uint(f);
  return (unsigned short)((b + 0x7fffu + ((b >> 16) & 1u)) >> 16);  // RNE
}

__device__ inline void gload_lds16(const void* g, void* l) {
  __builtin_amdgcn_global_load_lds(
      (const __attribute__((address_space(1))) void*)g,
      (__attribute__((address_space(3))) void*)l,
      16, 0, 0);
}

// ---------------- pass 1: transpose + f32->fp8 (HW) + row-stat partials ----------------
// grid: 128 m-supertiles x 16 c-tiles = 2048 blocks, 256 threads
// thread (mg = t>>2, cs = t&3): rows m0+4mg..+3, cols c0+16cs..+15
__global__ __launch_bounds__(256) void k_pass1(const float* __restrict__ x,
                                               unsigned char* __restrict__ xt,
                                               float* __restrict__ rssp,
                                               float* __restrict__ rs4p) {
  __shared__ unsigned int sh[64 * 68];  // [c 0..63][mg 0..63] u32, stride 68
  const int bid = blockIdx.x;
  const int m0 = (bid & 127) * 256;
  const int ct = bid >> 7;            // c-tile 0..15
  const int c0 = ct * 64;
  const int t = (int)threadIdx.x;
  const int mg = t >> 2;              // 4-row group 0..63
  const int cs = t & 3;               // 16-col chunk 0..3

  float ss[4] = {0.f, 0.f, 0.f, 0.f};
  float s4[4] = {0.f, 0.f, 0.f, 0.f};
  const float* xb = x + (size_t)(m0 + mg * 4) * D_DIM + c0 + cs * 16;

#pragma unroll
  for (int cg = 0; cg < 4; ++cg) {
    unsigned int p[4];
#pragma unroll
    for (int ri = 0; ri < 4; ++ri) {
      const float4 v = *(const float4*)(xb + (size_t)ri * D_DIM + cg * 4);
      const float q0 = v.x * v.x, q1 = v.y * v.y, q2 = v.z * v.z, q3 = v.w * v.w;
      ss[ri] += q0 + q1 + q2 + q3;
      s4[ri] += q0 * q0 + q1 * q1 + q2 * q2 + q3 * q3;
      unsigned int u = (unsigned int)__builtin_amdgcn_cvt_pk_fp8_f32(v.x, v.y, 0, false);
      p[ri] = (unsigned int)__builtin_amdgcn_cvt_pk_fp8_f32(v.z, v.w, (int)u, true);
    }
    // 4x4 byte transpose in registers
    const unsigned int t01l = __builtin_amdgcn_perm(p[1], p[0], 0x05010400u);
    const unsigned int t01h = __builtin_amdgcn_perm(p[1], p[0], 0x07030602u);
    const unsigned int t23l = __builtin_amdgcn_perm(p[3], p[2], 0x05010400u);
    const unsigned int t23h = __builtin_amdgcn_perm(p[3], p[2], 0x07030602u);
    const int cbase = (cs * 16 + cg * 4) * 68 + mg;
    sh[cbase + 0 * 68] = __builtin_amdgcn_perm(t23l, t01l, 0x05040100u);
    sh[cbase + 1 * 68] = __builtin_amdgcn_perm(t23l, t01l, 0x07060302u);
    sh[cbase + 2 * 68] = __builtin_amdgcn_perm(t23h, t01h, 0x05040100u);
    sh[cbase + 3 * 68] = __builtin_amdgcn_perm(t23h, t01h, 0x07060302u);
  }

  // stats: reduce across the 4 cs lanes (adjacent)
#pragma unroll
  for (int ri = 0; ri < 4; ++ri) {
    ss[ri] += __shfl_xor(ss[ri], 1, 4);
    ss[ri] += __shfl_xor(ss[ri], 2, 4);
    s4[ri] += __shfl_xor(s4[ri], 1, 4);
    s4[ri] += __shfl_xor(s4[ri], 2, 4);
  }
  if (cs == 0) {
#pragma unroll
    for (int ri = 0; ri < 4; ++ri) {
      rssp[ct * M_ROWS + m0 + mg * 4 + ri] = ss[ri];
      rs4p[ct * M_ROWS + m0 + mg * 4 + ri] = s4[ri];
    }
  }
  __syncthreads();

  // write-out: thread -> (xt row c0+c, 64B m-chunk ch); 256B contiguous per row
  const int c = t >> 2, ch = t & 3;
  const unsigned int* sp = &sh[c * 68 + ch * 16];
  const uint4 o0 = *(const uint4*)(sp + 0);
  const uint4 o1 = *(const uint4*)(sp + 4);
  const uint4 o2 = *(const uint4*)(sp + 8);
  const uint4 o3 = *(const uint4*)(sp + 12);
  unsigned char* dst = xt + ((size_t)(c0 + c) << 15) + m0 + ch * 64;
  *(uint4*)(dst + 0) = o0;
  *(uint4*)(dst + 16) = o1;
  *(uint4*)(dst + 32) = o2;
  *(uint4*)(dst + 48) = o3;
}

// ---------------- gemm: MX-fp8 (unit scale), BK=128, 2-phase dbuf, triangle ----------
// grid: S * 36 blocks, 256 threads (4 waves, 2x2 of 64x64)
__global__ __launch_bounds__(256) void k_gemm(const unsigned char* __restrict__ xt,
                                              unsigned int* __restrict__ cpart,
                                              int S, int swz) {
  __shared__ unsigned char As[2][16384];
  __shared__ unsigned char Bs[2][16384];
  const int bid = (int)blockIdx.x;
  int s, tidx;
  if (swz) {
    const int xcd = bid & 7;
    tidx = (bid >> 3) % NTILES;
    s = (bid / (8 * NTILES)) * 8 + xcd;
  } else {
    s = bid / NTILES;
    tidx = bid - s * NTILES;
  }
  int rem = tidx, ti = 0;
  while (rem >= 8 - ti) { rem -= 8 - ti; ++ti; }
  const int tj = ti + rem;
  const bool diag = (ti == tj);

  const int t = (int)threadIdx.x;
  const int l = t & 63, w = t >> 6;
  const int wr = w >> 1, wc = w & 1;
  const int r = l & 15, g = l >> 4;

  f32x4 acc[4][4];
#pragma unroll
  for (int mi = 0; mi < 4; ++mi)
#pragma unroll
    for (int ni = 0; ni < 4; ++ni) acc[mi][ni] = (f32x4){0.f, 0.f, 0.f, 0.f};

  const int srow = t >> 3;                          // 0..31
  const int sl = (((t & 7) ^ (srow & 7)) << 4);     // swizzled 16B slot offset
  const unsigned char* pa[4];
  const unsigned char* pb[4];
#pragma unroll
  for (int j = 0; j < 4; ++j) {
    pa[j] = xt + ((size_t)(ti * 128 + j * 32 + srow) << 15) + sl;
    pb[j] = xt + ((size_t)(tj * 128 + j * 32 + srow) << 15) + sl;
  }

#define STAGE(B, K) do { \
    _Pragma("unroll") \
    for (int j = 0; j < 4; ++j) { \
      gload_lds16(pa[j] + (K), &As[B][j * 4096 + t * 16]); \
      if (!diag) gload_lds16(pb[j] + (K), &Bs[B][j * 4096 + t * 16]); \
    } \
  } while (0)

  const int swb = r & 7;
  const int oA0 = (((2 * g + 0) ^ swb) << 4);
  const int oA1 = (((2 * g + 1) ^ swb) << 4);
  const int arow = (wr * 64 + r) * 128;
  const int brow = (wc * 64 + r) * 128;

#define COMPUTE(B, DS, SB, KN) do { \
    i32x4 alo[4], ahi[4], blo[4], bhi[4]; \
    const unsigned char* Ab = As[B]; \
    const unsigned char* Bb = diag ? As[B] : Bs[B]; \
    _Pragma("unroll") \
    for (int mi = 0; mi < 4; ++mi) { \
      alo[mi] = *(const i32x4*)(Ab + arow + mi * 2048 + oA0); \
      ahi[mi] = *(const i32x4*)(Ab + arow + mi * 2048 + oA1); \
      blo[mi] = *(const i32x4*)(Bb + brow + mi * 2048 + oA0); \
      bhi[mi] = *(const i32x4*)(Bb + brow + mi * 2048 + oA1); \
    } \
    if (DS) STAGE(SB, KN); \
    i32x8 a8[4], b8[4]; \
    _Pragma("unroll") \
    for (int mi = 0; mi < 4; ++mi) { \
      a8[mi] = (i32x8){alo[mi][0], alo[mi][1], alo[mi][2], alo[mi][3], \
                       ahi[mi][0], ahi[mi][1], ahi[mi][2], ahi[mi][3]}; \
      b8[mi] = (i32x8){blo[mi][0], blo[mi][1], blo[mi][2], blo[mi][3], \
                       bhi[mi][0], bhi[mi][1], bhi[mi][2], bhi[mi][3]}; \
    } \
    _Pragma("unroll") \
    for (int mi = 0; mi < 4; ++mi) \
      _Pragma("unroll") \
      for (int ni = 0; ni < 4; ++ni) \
        acc[mi][ni] = __builtin_amdgcn_mfma_scale_f32_16x16x128_f8f6f4( \
            a8[mi], b8[ni], acc[mi][ni], 0, 0, 0, 0x7F7F7F7Fu, 0, 0x7F7F7F7Fu); \
    __syncthreads(); \
  } while (0)

  const int kq = NKBS / S, kr = NKBS - kq * S;
  const int kb0 = s * kq + (s < kr ? s : kr);
  const int nkb = kq + (s < kr ? 1 : 0);
  size_t k = (size_t)kb0 * BK;

  STAGE(0, k);
  __syncthreads();
  int it = 0;
  for (; it + 2 <= nkb; it += 2) {
    COMPUTE(0, 1, 1, k + BK);
    COMPUTE(1, (it + 2 < nkb), 0, k + 2 * BK);
    k += 2 * BK;
  }
  if (it < nkb) COMPUTE(0, 0, 0, 0);

#undef STAGE
#undef COMPUTE

  // C/D layout: col = lane&15, row = (lane>>4)*4 + reg. Pack row-pairs as bf16.
  unsigned int* cp = cpart + ((size_t)s * NTILES + tidx) * CP_U32;
#pragma unroll
  for (int mi = 0; mi < 4; ++mi) {
    const int rowb = wr * 64 + mi * 16 + g * 4;   // even
#pragma unroll
    for (int ni = 0; ni < 4; ++ni) {
      const int col = wc * 64 + ni * 16 + r;
      const unsigned int w0 = (unsigned int)f2bf(acc[mi][ni][0]) |
                              ((unsigned int)f2bf(acc[mi][ni][1]) << 16);
      const unsigned int w1 = (unsigned int)f2bf(acc[mi][ni][2]) |
                              ((unsigned int)f2bf(acc[mi][ni][3]) << 16);
      cp[(size_t)((rowb >> 1) + 0) * 128 + col] = w0;
      cp[(size_t)((rowb >> 1) + 1) * 128 + col] = w1;
    }
  }
}

// ---------------- fused epi: sum partials -> upper write + mirrored lower write ------
// grid 36 tiles x 8 chunks = 288 blocks, 256 threads.
// thread: rowpair rp = chunk*8 + (t>>5), cols c..c+3 with c = 4*(t&31).
__global__ __launch_bounds__(256) void k_epi(const unsigned int* __restrict__ cpart,
                                             float* __restrict__ out, int S) {
  __shared__ float smir[16][132];
  const int b = (int)blockIdx.x;
  const int tile = b >> 3, chunk = b & 7;
  int rem = tile, ti = 0;
  while (rem >= 8 - ti) { rem -= 8 - ti; ++ti; }
  const int tj = ti + rem;
  const int t = (int)threadIdx.x;
  const int i4 = (b * 256 + t) * 4;
  const int rpl = t >> 5;             // rowpair-local 0..7
  const int c = (t & 31) * 4;

  const unsigned int* cp = cpart + i4;
  const size_t st = (size_t)NTILES * CP_U32;
  float lo0 = 0.f, lo1 = 0.f, lo2 = 0.f, lo3 = 0.f;
  float hi0 = 0.f, hi1 = 0.f, hi2 = 0.f, hi3 = 0.f;
  int s = 0;
  for (; s + 4 <= S; s += 4) {
    const uint4 v0 = *(const uint4*)(cp + (size_t)(s + 0) * st);
    const uint4 v1 = *(const uint4*)(cp + (size_t)(s + 1) * st);
    const uint4 v2 = *(const uint4*)(cp + (size_t)(s + 2) * st);
    const uint4 v3 = *(const uint4*)(cp + (size_t)(s + 3) * st);
    lo0 += __uint_as_float(v0.x << 16); hi0 += __uint_as_float(v0.x & 0xFFFF0000u);
    lo1 += __uint_as_float(v0.y << 16); hi1 += __uint_as_float(v0.y & 0xFFFF0000u);
    lo2 += __uint_as_float(v0.z << 16); hi2 += __uint_as_float(v0.z & 0xFFFF0000u);
    lo3 += __uint_as_float(v0.w << 16); hi3 += __uint_as_float(v0.w & 0xFFFF0000u);
    lo0 += __uint_as_float(v1.x << 16); hi0 += __uint_as_float(v1.x & 0xFFFF0000u);
    lo1 += __uint_as_float(v1.y << 16); hi1 += __uint_as_float(v1.y & 0xFFFF0000u);
    lo2 += __uint_as_float(v1.z << 16); hi2 += __uint_as_float(v1.z & 0xFFFF0000u);
    lo3 += __uint_as_float(v1.w << 16); hi3 += __uint_as_float(v1.w & 0xFFFF0000u);
    lo0 += __uint_as_float(v2.x << 16); hi0 += __uint_as_float(v2.x & 0xFFFF0000u);
    lo1 += __uint_as_float(v2.y << 16); hi1 += __uint_as_float(v2.y & 0xFFFF0000u);
    lo2 += __uint_as_float(v2.z << 16); hi2 += __uint_as_float(v2.z & 0xFFFF0000u);
    lo3 += __uint_as_float(v2.w << 16); hi3 += __uint_as_float(v2.w & 0xFFFF0000u);
    lo0 += __uint_as_float(v3.x << 16); hi0 += __uint_as_float(v3.x & 0xFFFF0000u);
    lo1 += __uint_as_float(v3.y << 16); hi1 += __uint_as_float(v3.y & 0xFFFF0000u);
    lo2 += __uint_as_float(v3.z << 16); hi2 += __uint_as_float(v3.z & 0xFFFF0000u);
    lo3 += __uint_as_float(v3.w << 16); hi3 += __uint_as_float(v3.w & 0xFFFF0000u);
  }
  for (; s < S; ++s) {
    const uint4 v = *(const uint4*)(cp + (size_t)s * st);
    lo0 += __uint_as_float(v.x << 16); hi0 += __uint_as_float(v.x & 0xFFFF0000u);
    lo1 += __uint_as_float(v.y << 16); hi1 += __uint_as_float(v.y & 0xFFFF0000u);
    lo2 += __uint_as_float(v.z << 16); hi2 += __uint_as_float(v.z & 0xFFFF0000u);
    lo3 += __uint_as_float(v.w << 16); hi3 += __uint_as_float(v.w & 0xFFFF0000u);
  }

  const float sc = 0.5f / (float)M_ROWS;
  f32x4 lo = (f32x4){lo0 * sc, lo1 * sc, lo2 * sc, lo3 * sc};
  f32x4 hi = (f32x4){hi0 * sc, hi1 * sc, hi2 * sc, hi3 * sc};

  const int gi = ti * 128 + chunk * 16 + 2 * rpl;
  const int gj = tj * 128 + c;
  if (ti == tj) {   // diag fixup: scaled - 0.5 on the diagonal
#pragma unroll
    for (int kk = 0; kk < 4; ++kk) {
      if (gi == gj + kk) lo[kk] -= 0.5f;
      if (gi + 1 == gj + kk) hi[kk] -= 0.5f;
    }
  }
  *(f32x4*)(out + (size_t)gi * D_DIM + gj) = lo;
  *(f32x4*)(out + (size_t)(gi + 1) * D_DIM + gj) = hi;

  if (ti != tj) {   // mirror lower block via LDS transpose
    const int jr = 2 * rpl;
    *(f32x4*)&smir[jr][c] = lo;
    *(f32x4*)&smir[jr + 1][c] = hi;
    __syncthreads();
    const int cc = t >> 1, j0 = (t & 1) * 8;
    f32x4 m0v, m1v;
    m0v[0] = smir[j0 + 0][cc]; m0v[1] = smir[j0 + 1][cc];
    m0v[2] = smir[j0 + 2][cc]; m0v[3] = smir[j0 + 3][cc];
    m1v[0] = smir[j0 + 4][cc]; m1v[1] = smir[j0 + 5][cc];
    m1v[2] = smir[j0 + 6][cc]; m1v[3] = smir[j0 + 7][cc];
    float* ob = out + (size_t)(tj * 128 + cc) * D_DIM + ti * 128 + chunk * 16 + j0;
    *(f32x4*)(ob + 0) = m0v;
    *(f32x4*)(ob + 4) = m1v;
  }
}

// ---------------- fin1: row stats reduce over 16 c-tiles + block partials ----------------
__global__ __launch_bounds__(256) void k_fin1(const float* __restrict__ rssp,
                                              const float* __restrict__ rs4p,
                                              float* __restrict__ scp) {
  __shared__ float sm[3][4];
  const int t = (int)threadIdx.x;
  const int m = (int)blockIdx.x * 256 + t;
  float a = 0.f, b = 0.f;
#pragma unroll
  for (int ct = 0; ct < 16; ++ct) {
    a += rssp[ct * M_ROWS + m];
    b += rs4p[ct * M_ROWS + m];
  }
  float corr = a * a - b;
#pragma unroll
  for (int off = 32; off; off >>= 1) {
    corr += __shfl_down(corr, off);
    a += __shfl_down(a, off);
    b += __shfl_down(b, off);
  }
  const int wv = t >> 6;
  if ((t & 63) == 0) { sm[0][wv] = corr; sm[1][wv] = a; sm[2][wv] = b; }
  __syncthreads();
  if (t == 0) {
    float c4 = 0.f, a4 = 0.f, b4 = 0.f;
#pragma unroll
    for (int i = 0; i < 4; ++i) { c4 += sm[0][i]; a4 += sm[1][i]; b4 += sm[2][i]; }
    scp[(int)blockIdx.x * 4 + 0] = c4;
    scp[(int)blockIdx.x * 4 + 1] = a4;
    scp[(int)blockIdx.x * 4 + 2] = b4;
  }
}

// ---------------- fin2: final scalars ----------------
__global__ __launch_bounds__(128) void k_fin2(const float* __restrict__ scp,
                                              float* __restrict__ out) {
  __shared__ float sm[3][2];
  const int t = (int)threadIdx.x;  // 0..127
  float c = scp[t * 4 + 0], a = scp[t * 4 + 1], b = scp[t * 4 + 2];
#pragma unroll
  for (int off = 32; off; off >>= 1) {
    c += __shfl_down(c, off);
    a += __shfl_down(a, off);
    b += __shfl_down(b, off);
  }
  const int wv = t >> 6;
  if ((t & 63) == 0) { sm[0][wv] = c; sm[1][wv] = a; sm[2][wv] = b; }
  __syncthreads();
  if (t == 0) {
    const double ct = (double)sm[0][0] + (double)sm[0][1];
    const double st = (double)sm[1][0] + (double)sm[1][1];
    const double qt = (double)sm[2][0] + (double)sm[2][1];
    const double N = (double)M_ROWS * (double)D_DIM;
    out[1048576] = (float)(ct / (double)M_ROWS / ((double)D_DIM * (double)D_DIM));
    out[1048577] = (float)((qt - 2.0 * st + N) / N);
  }
}

extern "C" void kernel_launch(void* const* d_in, const int* in_sizes, int n_in,
                              void* d_out, int out_size, void* d_ws, size_t ws_size,
                              hipStream_t stream) {
  (void)in_sizes; (void)n_in; (void)out_size;
  const float* x = (const float*)d_in[0];
  float* out = (float*)d_out;
  char* ws = (char*)d_ws;

  // ws layout:
  unsigned char* xt = (unsigned char*)ws;                   // 33,554,432 B (fp8)
  float* rssp = (float*)(ws + 33554432);                    //  2,097,152 B
  float* rs4p = (float*)(ws + 35651584);                    //  2,097,152 B
  float* scp  = (float*)(ws + 37748736);                    //      4,096 B
  unsigned int* cpart = (unsigned int*)(ws + 37752832);     //  S * 1,179,648 B
  const size_t base = 37752832;
  size_t avail = (ws_size > base) ? (ws_size - base) : 0;
  int S = (int)(avail / (sizeof(unsigned int) * NTILES * CP_U32));
  if (S > 32) S = 32;                 // 32 splits: 1152 blocks, 1MB L2 chunk/XCD
  int swz = 0;
  if (S >= 8) { S &= ~7; swz = 1; }   // multiple of 8 -> XCD-chunked decode
  if (S < 1) S = 1;

  k_pass1<<<2048, 256, 0, stream>>>(x, xt, rssp, rs4p);
  k_gemm<<<NTILES * S, 256, 0, stream>>>(xt, cpart, S, swz);
  k_epi<<<288, 256, 0, stream>>>(cpart, out, S);
  k_fin1<<<128, 256, 0, stream>>>(rssp, rs4p, scp);
  k_fin2<<<1, 128, 0, stream>>>(scp, out);
}

// Round 10
// 80.297 us; speedup vs baseline: 1.0985x; 1.0985x over previous
//
#include <hip/hip_runtime.h>
#include <hip/hip_bf16.h>
#include <stdint.h>
#include <stddef.h>

// DecorrLoss: grad = 0.5*mean_C(offdiag) + 0.5*diag(mean(x^2)-1), corr_loss, whit_loss
// x: f32 [8,4096,1024] -> [M=32768][D=1024]
//   pass1: f32 -> fp8 e4m3 (HW cvt_pk) transposed XT [D][M]; coalesced 256B row
//          loads, 4x4 register byte transpose (v_perm), conflict-free LDS, and
//          stats reduced via DPP ladder (VALU pipe, no ds_swizzle storm).
//   gemm : C = XT*XT^T via MX-scaled fp8 MFMA 16x16x128 (unit scales), 36 upper-
//          triangle 128x128 tiles, split-K S=32, XCD-chunked, BK=128, 2-phase
//          dbuf LDS, slot^row swizzle via pre-swizzled global src. bf16-packed C.
//   epi  : FUSED: sum S partials -> upper write (+diag-0.5 fixup) + LDS-transposed
//          mirror write of the lower block.
//   fin1/fin2: deterministic scalar losses (f32 path, unaffected by fp8)

#define D_DIM 1024
#define M_ROWS 32768
#define BK 128
#define NKBS (M_ROWS / BK)         // 256 K-blocks of 128
#define NTILES 36                  // 8*9/2 triangle tiles
#define TILE_ELEMS 16384           // 128*128
#define CP_U32 8192                // u32 per packed tile (128*128/2)

typedef __attribute__((ext_vector_type(4))) float f32x4;
typedef __attribute__((ext_vector_type(4))) int i32x4;
typedef __attribute__((ext_vector_type(8))) int i32x8;

__device__ inline unsigned short f2bf(float f) {
  unsigned int b = __float_as_uint(f);
  return (unsigned short)((b + 0x7fffu + ((b >> 16) & 1u)) >> 16);  // RNE
}

__device__ inline void gload_lds16(const void* g, void* l) {
  __builtin_amdgcn_global_load_lds(
      (const __attribute__((address_space(1))) void*)g,
      (__attribute__((address_space(3))) void*)l,
      16, 0, 0);
}

// sum over each aligned 16-lane group, all-lanes result; VALU DPP, no LDS ops.
// xor1=quad_perm(1,0,3,2)=0xB1, xor2=quad_perm(2,3,0,1)=0x4E,
// xor4=row_half_mirror=0x141, xor8=row_mirror=0x140
__device__ inline float dppsum16(float v) {
  v += __uint_as_float((unsigned)__builtin_amdgcn_update_dpp(
      0, (int)__float_as_uint(v), 0xB1, 0xF, 0xF, true));
  v += __uint_as_float((unsigned)__builtin_amdgcn_update_dpp(
      0, (int)__float_as_uint(v), 0x4E, 0xF, 0xF, true));
  v += __uint_as_float((unsigned)__builtin_amdgcn_update_dpp(
      0, (int)__float_as_uint(v), 0x141, 0xF, 0xF, true));
  v += __uint_as_float((unsigned)__builtin_amdgcn_update_dpp(
      0, (int)__float_as_uint(v), 0x140, 0xF, 0xF, true));
  return v;
}

// ---------------- pass 1: transpose + f32->fp8 (HW) + row-stat partials ----------------
// grid: 512 m-tiles x 16 c-tiles = 8192 blocks, 256 threads
// thread (q = t>>4, cg = t&15): rows m0+4q..+3, cols c0+4cg..+3
__global__ __launch_bounds__(256) void k_pass1(const float* __restrict__ x,
                                               unsigned char* __restrict__ xt,
                                               float* __restrict__ rssp,
                                               float* __restrict__ rs4p) {
  __shared__ unsigned int sh32[16 * 68];  // [m-group 0..15][64 cols + 4 pad] u32
  const int bid = blockIdx.x;
  const int m0 = (bid & 511) * 64;
  const int ct = bid >> 9;            // c-tile 0..15
  const int c0 = ct * 64;
  const int t = (int)threadIdx.x;
  const int q = t >> 4;               // m-group (4 rows); 16-lane-aligned for DPP
  const int cg = t & 15;              // col group (4 cols)

  unsigned int p[4];
  float ss[4], s4[4];
#pragma unroll
  for (int mi = 0; mi < 4; ++mi) {
    const float4 v = *(const float4*)(x + (size_t)(m0 + q * 4 + mi) * D_DIM + c0 + cg * 4);
    const float q0 = v.x * v.x, q1 = v.y * v.y, q2 = v.z * v.z, q3 = v.w * v.w;
    ss[mi] = q0 + q1 + q2 + q3;
    s4[mi] = q0 * q0 + q1 * q1 + q2 * q2 + q3 * q3;
    unsigned int u = (unsigned int)__builtin_amdgcn_cvt_pk_fp8_f32(v.x, v.y, 0, false);
    p[mi] = (unsigned int)__builtin_amdgcn_cvt_pk_fp8_f32(v.z, v.w, (int)u, true);
  }
  // stats reduce across the 16 cg lanes — DPP ladder on the VALU pipe
#pragma unroll
  for (int mi = 0; mi < 4; ++mi) {
    ss[mi] = dppsum16(ss[mi]);
    s4[mi] = dppsum16(s4[mi]);
  }
  if (cg == 0) {
#pragma unroll
    for (int mi = 0; mi < 4; ++mi) {
      rssp[ct * M_ROWS + m0 + q * 4 + mi] = ss[mi];
      rs4p[ct * M_ROWS + m0 + q * 4 + mi] = s4[mi];
    }
  }

  // 4x4 byte transpose in registers
  const unsigned int t01l = __builtin_amdgcn_perm(p[1], p[0], 0x05010400u);
  const unsigned int t01h = __builtin_amdgcn_perm(p[1], p[0], 0x07030602u);
  const unsigned int t23l = __builtin_amdgcn_perm(p[3], p[2], 0x05010400u);
  const unsigned int t23h = __builtin_amdgcn_perm(p[3], p[2], 0x07030602u);
  uint4 w;
  w.x = __builtin_amdgcn_perm(t23l, t01l, 0x05040100u);
  w.y = __builtin_amdgcn_perm(t23l, t01l, 0x07060302u);
  w.z = __builtin_amdgcn_perm(t23h, t01h, 0x05040100u);
  w.w = __builtin_amdgcn_perm(t23h, t01h, 0x07060302u);
  *(uint4*)&sh32[q * 68 + cg * 4] = w;
  __syncthreads();

  // write-out: lane -> (xt row c0+c, 16B m-chunk mh); wave covers 16 full 64B lines
  const int c = t >> 2, mh = t & 3;
  uint4 o;
  o.x = sh32[(mh * 4 + 0) * 68 + c];
  o.y = sh32[(mh * 4 + 1) * 68 + c];
  o.z = sh32[(mh * 4 + 2) * 68 + c];
  o.w = sh32[(mh * 4 + 3) * 68 + c];
  *(uint4*)(xt + ((size_t)(c0 + c) << 15) + m0 + mh * 16) = o;
}

// ---------------- gemm: MX-fp8 (unit scale), BK=128, 2-phase dbuf, triangle ----------
// grid: S * 36 blocks, 256 threads (4 waves, 2x2 of 64x64)
__global__ __launch_bounds__(256) void k_gemm(const unsigned char* __restrict__ xt,
                                              unsigned int* __restrict__ cpart,
                                              int S, int swz) {
  __shared__ unsigned char As[2][16384];
  __shared__ unsigned char Bs[2][16384];
  const int bid = (int)blockIdx.x;
  int s, tidx;
  if (swz) {
    const int xcd = bid & 7;
    tidx = (bid >> 3) % NTILES;
    s = (bid / (8 * NTILES)) * 8 + xcd;
  } else {
    s = bid / NTILES;
    tidx = bid - s * NTILES;
  }
  int rem = tidx, ti = 0;
  while (rem >= 8 - ti) { rem -= 8 - ti; ++ti; }
  const int tj = ti + rem;
  const bool diag = (ti == tj);

  const int t = (int)threadIdx.x;
  const int l = t & 63, w = t >> 6;
  const int wr = w >> 1, wc = w & 1;
  const int r = l & 15, g = l >> 4;

  f32x4 acc[4][4];
#pragma unroll
  for (int mi = 0; mi < 4; ++mi)
#pragma unroll
    for (int ni = 0; ni < 4; ++ni) acc[mi][ni] = (f32x4){0.f, 0.f, 0.f, 0.f};

  const int srow = t >> 3;                          // 0..31
  const int sl = (((t & 7) ^ (srow & 7)) << 4);     // swizzled 16B slot offset
  const unsigned char* pa[4];
  const unsigned char* pb[4];
#pragma unroll
  for (int j = 0; j < 4; ++j) {
    pa[j] = xt + ((size_t)(ti * 128 + j * 32 + srow) << 15) + sl;
    pb[j] = xt + ((size_t)(tj * 128 + j * 32 + srow) << 15) + sl;
  }

#define STAGE(B, K) do { \
    _Pragma("unroll") \
    for (int j = 0; j < 4; ++j) { \
      gload_lds16(pa[j] + (K), &As[B][j * 4096 + t * 16]); \
      if (!diag) gload_lds16(pb[j] + (K), &Bs[B][j * 4096 + t * 16]); \
    } \
  } while (0)

  const int swb = r & 7;
  const int oA0 = (((2 * g + 0) ^ swb) << 4);
  const int oA1 = (((2 * g + 1) ^ swb) << 4);
  const int arow = (wr * 64 + r) * 128;
  const int brow = (wc * 64 + r) * 128;

#define COMPUTE(B, DS, SB, KN) do { \
    i32x4 alo[4], ahi[4], blo[4], bhi[4]; \
    const unsigned char* Ab = As[B]; \
    const unsigned char* Bb = diag ? As[B] : Bs[B]; \
    _Pragma("unroll") \
    for (int mi = 0; mi < 4; ++mi) { \
      alo[mi] = *(const i32x4*)(Ab + arow + mi * 2048 + oA0); \
      ahi[mi] = *(const i32x4*)(Ab + arow + mi * 2048 + oA1); \
      blo[mi] = *(const i32x4*)(Bb + brow + mi * 2048 + oA0); \
      bhi[mi] = *(const i32x4*)(Bb + brow + mi * 2048 + oA1); \
    } \
    if (DS) STAGE(SB, KN); \
    i32x8 a8[4], b8[4]; \
    _Pragma("unroll") \
    for (int mi = 0; mi < 4; ++mi) { \
      a8[mi] = (i32x8){alo[mi][0], alo[mi][1], alo[mi][2], alo[mi][3], \
                       ahi[mi][0], ahi[mi][1], ahi[mi][2], ahi[mi][3]}; \
      b8[mi] = (i32x8){blo[mi][0], blo[mi][1], blo[mi][2], blo[mi][3], \
                       bhi[mi][0], bhi[mi][1], bhi[mi][2], bhi[mi][3]}; \
    } \
    _Pragma("unroll") \
    for (int mi = 0; mi < 4; ++mi) \
      _Pragma("unroll") \
      for (int ni = 0; ni < 4; ++ni) \
        acc[mi][ni] = __builtin_amdgcn_mfma_scale_f32_16x16x128_f8f6f4( \
            a8[mi], b8[ni], acc[mi][ni], 0, 0, 0, 0x7F7F7F7Fu, 0, 0x7F7F7F7Fu); \
    __syncthreads(); \
  } while (0)

  const int kq = NKBS / S, kr = NKBS - kq * S;
  const int kb0 = s * kq + (s < kr ? s : kr);
  const int nkb = kq + (s < kr ? 1 : 0);
  size_t k = (size_t)kb0 * BK;

  STAGE(0, k);
  __syncthreads();
  int it = 0;
  for (; it + 2 <= nkb; it += 2) {
    COMPUTE(0, 1, 1, k + BK);
    COMPUTE(1, (it + 2 < nkb), 0, k + 2 * BK);
    k += 2 * BK;
  }
  if (it < nkb) COMPUTE(0, 0, 0, 0);

#undef STAGE
#undef COMPUTE

  // C/D layout: col = lane&15, row = (lane>>4)*4 + reg. Pack row-pairs as bf16.
  unsigned int* cp = cpart + ((size_t)s * NTILES + tidx) * CP_U32;
#pragma unroll
  for (int mi = 0; mi < 4; ++mi) {
    const int rowb = wr * 64 + mi * 16 + g * 4;   // even
#pragma unroll
    for (int ni = 0; ni < 4; ++ni) {
      const int col = wc * 64 + ni * 16 + r;
      const unsigned int w0 = (unsigned int)f2bf(acc[mi][ni][0]) |
                              ((unsigned int)f2bf(acc[mi][ni][1]) << 16);
      const unsigned int w1 = (unsigned int)f2bf(acc[mi][ni][2]) |
                              ((unsigned int)f2bf(acc[mi][ni][3]) << 16);
      cp[(size_t)((rowb >> 1) + 0) * 128 + col] = w0;
      cp[(size_t)((rowb >> 1) + 1) * 128 + col] = w1;
    }
  }
}

// ---------------- fused epi: sum partials -> upper write + mirrored lower write ------
// grid 36 tiles x 8 chunks = 288 blocks, 256 threads.
__global__ __launch_bounds__(256) void k_epi(const unsigned int* __restrict__ cpart,
                                             float* __restrict__ out, int S) {
  __shared__ float smir[16][132];
  const int b = (int)blockIdx.x;
  const int tile = b >> 3, chunk = b & 7;
  int rem = tile, ti = 0;
  while (rem >= 8 - ti) { rem -= 8 - ti; ++ti; }
  const int tj = ti + rem;
  const int t = (int)threadIdx.x;
  const int i4 = (b * 256 + t) * 4;
  const int rpl = t >> 5;             // rowpair-local 0..7
  const int c = (t & 31) * 4;

  const unsigned int* cp = cpart + i4;
  const size_t st = (size_t)NTILES * CP_U32;
  float lo0 = 0.f, lo1 = 0.f, lo2 = 0.f, lo3 = 0.f;
  float hi0 = 0.f, hi1 = 0.f, hi2 = 0.f, hi3 = 0.f;
  for (int s = 0; s < S; ++s) {
    const uint4 v = *(const uint4*)(cp + (size_t)s * st);
    lo0 += __uint_as_float(v.x << 16); hi0 += __uint_as_float(v.x & 0xFFFF0000u);
    lo1 += __uint_as_float(v.y << 16); hi1 += __uint_as_float(v.y & 0xFFFF0000u);
    lo2 += __uint_as_float(v.z << 16); hi2 += __uint_as_float(v.z & 0xFFFF0000u);
    lo3 += __uint_as_float(v.w << 16); hi3 += __uint_as_float(v.w & 0xFFFF0000u);
  }

  const float sc = 0.5f / (float)M_ROWS;
  f32x4 lo = (f32x4){lo0 * sc, lo1 * sc, lo2 * sc, lo3 * sc};
  f32x4 hi = (f32x4){hi0 * sc, hi1 * sc, hi2 * sc, hi3 * sc};

  const int gi = ti * 128 + chunk * 16 + 2 * rpl;
  const int gj = tj * 128 + c;
  if (ti == tj) {   // diag fixup: scaled - 0.5 on the diagonal
#pragma unroll
    for (int kk = 0; kk < 4; ++kk) {
      if (gi == gj + kk) lo[kk] -= 0.5f;
      if (gi + 1 == gj + kk) hi[kk] -= 0.5f;
    }
  }
  *(f32x4*)(out + (size_t)gi * D_DIM + gj) = lo;
  *(f32x4*)(out + (size_t)(gi + 1) * D_DIM + gj) = hi;

  if (ti != tj) {   // mirror lower block via LDS transpose
    const int jr = 2 * rpl;
    *(f32x4*)&smir[jr][c] = lo;
    *(f32x4*)&smir[jr + 1][c] = hi;
    __syncthreads();
    const int cc = t >> 1, j0 = (t & 1) * 8;
    f32x4 m0v, m1v;
    m0v[0] = smir[j0 + 0][cc]; m0v[1] = smir[j0 + 1][cc];
    m0v[2] = smir[j0 + 2][cc]; m0v[3] = smir[j0 + 3][cc];
    m1v[0] = smir[j0 + 4][cc]; m1v[1] = smir[j0 + 5][cc];
    m1v[2] = smir[j0 + 6][cc]; m1v[3] = smir[j0 + 7][cc];
    float* ob = out + (size_t)(tj * 128 + cc) * D_DIM + ti * 128 + chunk * 16 + j0;
    *(f32x4*)(ob + 0) = m0v;
    *(f32x4*)(ob + 4) = m1v;
  }
}

// ---------------- fin1: row stats reduce over 16 c-tiles + block partials ----------------
__global__ __launch_bounds__(256) void k_fin1(const float* __restrict__ rssp,
                                              const float* __restrict__ rs4p,
                                              float* __restrict__ scp) {
  __shared__ float sm[3][4];
  const int t = (int)threadIdx.x;
  const int m = (int)blockIdx.x * 256 + t;
  float a = 0.f, b = 0.f;
#pragma unroll
  for (int ct = 0; ct < 16; ++ct) {
    a += rssp[ct * M_ROWS + m];
    b += rs4p[ct * M_ROWS + m];
  }
  float corr = a * a - b;
#pragma unroll
  for (int off = 32; off; off >>= 1) {
    corr += __shfl_down(corr, off);
    a += __shfl_down(a, off);
    b += __shfl_down(b, off);
  }
  const int wv = t >> 6;
  if ((t & 63) == 0) { sm[0][wv] = corr; sm[1][wv] = a; sm[2][wv] = b; }
  __syncthreads();
  if (t == 0) {
    float c4 = 0.f, a4 = 0.f, b4 = 0.f;
#pragma unroll
    for (int i = 0; i < 4; ++i) { c4 += sm[0][i]; a4 += sm[1][i]; b4 += sm[2][i]; }
    scp[(int)blockIdx.x * 4 + 0] = c4;
    scp[(int)blockIdx.x * 4 + 1] = a4;
    scp[(int)blockIdx.x * 4 + 2] = b4;
  }
}

// ---------------- fin2: final scalars ----------------
__global__ __launch_bounds__(128) void k_fin2(const float* __restrict__ scp,
                                              float* __restrict__ out) {
  __shared__ float sm[3][2];
  const int t = (int)threadIdx.x;  // 0..127
  float c = scp[t * 4 + 0], a = scp[t * 4 + 1], b = scp[t * 4 + 2];
#pragma unroll
  for (int off = 32; off; off >>= 1) {
    c += __shfl_down(c, off);
    a += __shfl_down(a, off);
    b += __shfl_down(b, off);
  }
  const int wv = t >> 6;
  if ((t & 63) == 0) { sm[0][wv] = c; sm[1][wv] = a; sm[2][wv] = b; }
  __syncthreads();
  if (t == 0) {
    const double ct = (double)sm[0][0] + (double)sm[0][1];
    const double st = (double)sm[1][0] + (double)sm[1][1];
    const double qt = (double)sm[2][0] + (double)sm[2][1];
    const double N = (double)M_ROWS * (double)D_DIM;
    out[1048576] = (float)(ct / (double)M_ROWS / ((double)D_DIM * (double)D_DIM));
    out[1048577] = (float)((qt - 2.0 * st + N) / N);
  }
}

extern "C" void kernel_launch(void* const* d_in, const int* in_sizes, int n_in,
                              void* d_out, int out_size, void* d_ws, size_t ws_size,
                              hipStream_t stream) {
  (void)in_sizes; (void)n_in; (void)out_size;
  const float* x = (const float*)d_in[0];
  float* out = (float*)d_out;
  char* ws = (char*)d_ws;

  // ws layout:
  unsigned char* xt = (unsigned char*)ws;                   // 33,554,432 B (fp8)
  float* rssp = (float*)(ws + 33554432);                    //  2,097,152 B
  float* rs4p = (float*)(ws + 35651584);                    //  2,097,152 B
  float* scp  = (float*)(ws + 37748736);                    //      4,096 B
  unsigned int* cpart = (unsigned int*)(ws + 37752832);     //  S * 1,179,648 B
  const size_t base = 37752832;
  size_t avail = (ws_size > base) ? (ws_size - base) : 0;
  int S = (int)(avail / (sizeof(unsigned int) * NTILES * CP_U32));
  if (S > 32) S = 32;                 // 32 splits: 1152 blocks, 1MB L2 chunk/XCD
  int swz = 0;
  if (S >= 8) { S &= ~7; swz = 1; }   // multiple of 8 -> XCD-chunked decode
  if (S < 1) S = 1;

  k_pass1<<<8192, 256, 0, stream>>>(x, xt, rssp, rs4p);
  k_gemm<<<NTILES * S, 256, 0, stream>>>(xt, cpart, S, swz);
  k_epi<<<288, 256, 0, stream>>>(cpart, out, S);
  k_fin1<<<128, 256, 0, stream>>>(rssp, rs4p, scp);
  k_fin2<<<1, 128, 0, stream>>>(scp, out);
}

// Round 11
// 79.480 us; speedup vs baseline: 1.1098x; 1.0103x over previous
//
#include <hip/hip_runtime.h>
#include <hip/hip_bf16.h>
#include <stdint.h>
#include <stddef.h>

// DecorrLoss: grad = 0.5*mean_C(offdiag) + 0.5*diag(mean(x^2)-1), corr_loss, whit_loss
// x: f32 [8,4096,1024] -> [M=32768][D=1024]
//   pass1: f32 -> fp8 e4m3 (HW cvt_pk) TILE-LINEAR transposed XT; 4x4 register
//          byte transpose (v_perm), DPP-ladder stats, and a fully-contiguous
//          4KB-per-block write (xt tile layout: [ct][mt][c_local*64+m_local]).
//   gemm : C = XT*XT^T via MX-scaled fp8 MFMA 16x16x128 (unit scales), 36 upper-
//          triangle 128x128 tiles, split-K S=32, XCD-chunked, BK=128, 2-phase
//          dbuf LDS, slot^row swizzle on the (tiled) global source. bf16-packed C.
//   epi  : FUSED: sum S partials -> upper write (+diag-0.5 fixup) + LDS-transposed
//          mirror write of the lower block.
//   fin1/fin2: deterministic scalar losses (f32 path, unaffected by fp8)

#define D_DIM 1024
#define M_ROWS 32768
#define BK 128
#define NKBS (M_ROWS / BK)         // 256 K-blocks of 128
#define NTILES 36                  // 8*9/2 triangle tiles
#define TILE_ELEMS 16384           // 128*128
#define CP_U32 8192                // u32 per packed tile (128*128/2)
#define CT_STRIDE 2097152          // bytes per c-tile group in xt (512*4096)

typedef __attribute__((ext_vector_type(4))) float f32x4;
typedef __attribute__((ext_vector_type(4))) int i32x4;
typedef __attribute__((ext_vector_type(8))) int i32x8;

__device__ inline unsigned short f2bf(float f) {
  unsigned int b = __float_as_uint(f);
  return (unsigned short)((b + 0x7fffu + ((b >> 16) & 1u)) >> 16);  // RNE
}

__device__ inline void gload_lds16(const void* g, void* l) {
  __builtin_amdgcn_global_load_lds(
      (const __attribute__((address_space(1))) void*)g,
      (__attribute__((address_space(3))) void*)l,
      16, 0, 0);
}

// sum over each aligned 16-lane group, all-lanes result; VALU DPP, no LDS ops.
__device__ inline float dppsum16(float v) {
  v += __uint_as_float((unsigned)__builtin_amdgcn_update_dpp(
      0, (int)__float_as_uint(v), 0xB1, 0xF, 0xF, true));   // xor1 quad_perm
  v += __uint_as_float((unsigned)__builtin_amdgcn_update_dpp(
      0, (int)__float_as_uint(v), 0x4E, 0xF, 0xF, true));   // xor2 quad_perm
  v += __uint_as_float((unsigned)__builtin_amdgcn_update_dpp(
      0, (int)__float_as_uint(v), 0x141, 0xF, 0xF, true));  // xor4 row_half_mirror
  v += __uint_as_float((unsigned)__builtin_amdgcn_update_dpp(
      0, (int)__float_as_uint(v), 0x140, 0xF, 0xF, true));  // xor8 row_mirror
  return v;
}

// ---------------- pass 1: transpose + f32->fp8 (HW) + row-stat partials ----------------
// grid: 512 m-tiles x 16 c-tiles = 8192 blocks, 256 threads
// thread (q = t>>4, cg = t&15): rows m0+4q..+3, cols c0+4cg..+3
__global__ __launch_bounds__(256) void k_pass1(const float* __restrict__ x,
                                               unsigned char* __restrict__ xt,
                                               float* __restrict__ rssp,
                                               float* __restrict__ rs4p) {
  __shared__ unsigned int sh32[16 * 68];  // [m-group 0..15][64 cols + 4 pad] u32
  const int bid = blockIdx.x;
  const int mt = bid & 511;
  const int m0 = mt * 64;
  const int ct = bid >> 9;            // c-tile 0..15
  const int c0 = ct * 64;
  const int t = (int)threadIdx.x;
  const int q = t >> 4;               // m-group (4 rows); 16-lane-aligned for DPP
  const int cg = t & 15;              // col group (4 cols)

  unsigned int p[4];
  float ss[4], s4[4];
#pragma unroll
  for (int mi = 0; mi < 4; ++mi) {
    const float4 v = *(const float4*)(x + (size_t)(m0 + q * 4 + mi) * D_DIM + c0 + cg * 4);
    const float q0 = v.x * v.x, q1 = v.y * v.y, q2 = v.z * v.z, q3 = v.w * v.w;
    ss[mi] = q0 + q1 + q2 + q3;
    s4[mi] = q0 * q0 + q1 * q1 + q2 * q2 + q3 * q3;
    unsigned int u = (unsigned int)__builtin_amdgcn_cvt_pk_fp8_f32(v.x, v.y, 0, false);
    p[mi] = (unsigned int)__builtin_amdgcn_cvt_pk_fp8_f32(v.z, v.w, (int)u, true);
  }
  // stats reduce across the 16 cg lanes — DPP ladder on the VALU pipe
#pragma unroll
  for (int mi = 0; mi < 4; ++mi) {
    ss[mi] = dppsum16(ss[mi]);
    s4[mi] = dppsum16(s4[mi]);
  }
  if (cg == 0) {
#pragma unroll
    for (int mi = 0; mi < 4; ++mi) {
      rssp[ct * M_ROWS + m0 + q * 4 + mi] = ss[mi];
      rs4p[ct * M_ROWS + m0 + q * 4 + mi] = s4[mi];
    }
  }

  // 4x4 byte transpose in registers
  const unsigned int t01l = __builtin_amdgcn_perm(p[1], p[0], 0x05010400u);
  const unsigned int t01h = __builtin_amdgcn_perm(p[1], p[0], 0x07030602u);
  const unsigned int t23l = __builtin_amdgcn_perm(p[3], p[2], 0x05010400u);
  const unsigned int t23h = __builtin_amdgcn_perm(p[3], p[2], 0x07030602u);
  uint4 w;
  w.x = __builtin_amdgcn_perm(t23l, t01l, 0x05040100u);
  w.y = __builtin_amdgcn_perm(t23l, t01l, 0x07060302u);
  w.z = __builtin_amdgcn_perm(t23h, t01h, 0x05040100u);
  w.w = __builtin_amdgcn_perm(t23h, t01h, 0x07060302u);
  *(uint4*)&sh32[q * 68 + cg * 4] = w;
  __syncthreads();

  // write-out: TILE-LINEAR. Block's 64x64 fp8 tile (c_local*64 + m_local) goes to
  // one contiguous 4KB run; thread t emits 16B at offset t*16.
  // c_local = t>>2, m-groups (t&3)*4..+3 — same LDS reads as the row-major version.
  const int c = t >> 2, mh = t & 3;
  uint4 o;
  o.x = sh32[(mh * 4 + 0) * 68 + c];
  o.y = sh32[(mh * 4 + 1) * 68 + c];
  o.z = sh32[(mh * 4 + 2) * 68 + c];
  o.w = sh32[(mh * 4 + 3) * 68 + c];
  *(uint4*)(xt + (size_t)ct * CT_STRIDE + ((size_t)mt << 12) + t * 16) = o;
}

// ---------------- gemm: MX-fp8 (unit scale), BK=128, 2-phase dbuf, triangle ----------
// grid: S * 36 blocks, 256 threads (4 waves, 2x2 of 64x64)
// xt is tile-linear: byte(row, k) = (row>>6)*CT_STRIDE + (k>>6)*4096 + (row&63)*64 + (k&63)
__global__ __launch_bounds__(256) void k_gemm(const unsigned char* __restrict__ xt,
                                              unsigned int* __restrict__ cpart,
                                              int S, int swz) {
  __shared__ unsigned char As[2][16384];
  __shared__ unsigned char Bs[2][16384];
  const int bid = (int)blockIdx.x;
  int s, tidx;
  if (swz) {
    const int xcd = bid & 7;
    tidx = (bid >> 3) % NTILES;
    s = (bid / (8 * NTILES)) * 8 + xcd;
  } else {
    s = bid / NTILES;
    tidx = bid - s * NTILES;
  }
  int rem = tidx, ti = 0;
  while (rem >= 8 - ti) { rem -= 8 - ti; ++ti; }
  const int tj = ti + rem;
  const bool diag = (ti == tj);

  const int t = (int)threadIdx.x;
  const int l = t & 63, w = t >> 6;
  const int wr = w >> 1, wc = w & 1;
  const int r = l & 15, g = l >> 4;

  f32x4 acc[4][4];
#pragma unroll
  for (int mi = 0; mi < 4; ++mi)
#pragma unroll
    for (int ni = 0; ni < 4; ++ni) acc[mi][ni] = (f32x4){0.f, 0.f, 0.f, 0.f};

  // staging (logical layout identical to before; only global address map changed):
  // thread t -> LDS [j*4096 + t*16] = row (j*32 + srow), swizzled slot (t&7)^(srow&7).
  const int srow = t >> 3;                          // 0..31
  const int slot = (t & 7) ^ (srow & 7);            // swizzled 16B slot 0..7
  const int slterm = (slot >> 2) * 4096 + (slot & 3) * 16;  // tiled addr of slot*16
  const unsigned char* pa[4];
  const unsigned char* pb[4];
#pragma unroll
  for (int j = 0; j < 4; ++j) {
    const int rowa = ti * 128 + j * 32 + srow;
    const int rowb_ = tj * 128 + j * 32 + srow;
    pa[j] = xt + (size_t)(rowa >> 6) * CT_STRIDE + (rowa & 63) * 64 + slterm;
    pb[j] = xt + (size_t)(rowb_ >> 6) * CT_STRIDE + (rowb_ & 63) * 64 + slterm;
  }

  // K is a byte-k multiple of 128; tiled k-advance = K*64 bytes.
#define STAGE(B, K) do { \
    const size_t koff = (size_t)(K) << 6; \
    _Pragma("unroll") \
    for (int j = 0; j < 4; ++j) { \
      gload_lds16(pa[j] + koff, &As[B][j * 4096 + t * 16]); \
      if (!diag) gload_lds16(pb[j] + koff, &Bs[B][j * 4096 + t * 16]); \
    } \
  } while (0)

  const int swb = r & 7;
  const int oA0 = (((2 * g + 0) ^ swb) << 4);
  const int oA1 = (((2 * g + 1) ^ swb) << 4);
  const int arow = (wr * 64 + r) * 128;
  const int brow = (wc * 64 + r) * 128;

#define COMPUTE(B, DS, SB, KN) do { \
    i32x4 alo[4], ahi[4], blo[4], bhi[4]; \
    const unsigned char* Ab = As[B]; \
    const unsigned char* Bb = diag ? As[B] : Bs[B]; \
    _Pragma("unroll") \
    for (int mi = 0; mi < 4; ++mi) { \
      alo[mi] = *(const i32x4*)(Ab + arow + mi * 2048 + oA0); \
      ahi[mi] = *(const i32x4*)(Ab + arow + mi * 2048 + oA1); \
      blo[mi] = *(const i32x4*)(Bb + brow + mi * 2048 + oA0); \
      bhi[mi] = *(const i32x4*)(Bb + brow + mi * 2048 + oA1); \
    } \
    if (DS) STAGE(SB, KN); \
    i32x8 a8[4], b8[4]; \
    _Pragma("unroll") \
    for (int mi = 0; mi < 4; ++mi) { \
      a8[mi] = (i32x8){alo[mi][0], alo[mi][1], alo[mi][2], alo[mi][3], \
                       ahi[mi][0], ahi[mi][1], ahi[mi][2], ahi[mi][3]}; \
      b8[mi] = (i32x8){blo[mi][0], blo[mi][1], blo[mi][2], blo[mi][3], \
                       bhi[mi][0], bhi[mi][1], bhi[mi][2], bhi[mi][3]}; \
    } \
    _Pragma("unroll") \
    for (int mi = 0; mi < 4; ++mi) \
      _Pragma("unroll") \
      for (int ni = 0; ni < 4; ++ni) \
        acc[mi][ni] = __builtin_amdgcn_mfma_scale_f32_16x16x128_f8f6f4( \
            a8[mi], b8[ni], acc[mi][ni], 0, 0, 0, 0x7F7F7F7Fu, 0, 0x7F7F7F7Fu); \
    __syncthreads(); \
  } while (0)

  const int kq = NKBS / S, kr = NKBS - kq * S;
  const int kb0 = s * kq + (s < kr ? s : kr);
  const int nkb = kq + (s < kr ? 1 : 0);
  size_t k = (size_t)kb0 * BK;

  STAGE(0, k);
  __syncthreads();
  int it = 0;
  for (; it + 2 <= nkb; it += 2) {
    COMPUTE(0, 1, 1, k + BK);
    COMPUTE(1, (it + 2 < nkb), 0, k + 2 * BK);
    k += 2 * BK;
  }
  if (it < nkb) COMPUTE(0, 0, 0, 0);

#undef STAGE
#undef COMPUTE

  // C/D layout: col = lane&15, row = (lane>>4)*4 + reg. Pack row-pairs as bf16.
  unsigned int* cp = cpart + ((size_t)s * NTILES + tidx) * CP_U32;
#pragma unroll
  for (int mi = 0; mi < 4; ++mi) {
    const int rowb = wr * 64 + mi * 16 + g * 4;   // even
#pragma unroll
    for (int ni = 0; ni < 4; ++ni) {
      const int col = wc * 64 + ni * 16 + r;
      const unsigned int w0 = (unsigned int)f2bf(acc[mi][ni][0]) |
                              ((unsigned int)f2bf(acc[mi][ni][1]) << 16);
      const unsigned int w1 = (unsigned int)f2bf(acc[mi][ni][2]) |
                              ((unsigned int)f2bf(acc[mi][ni][3]) << 16);
      cp[(size_t)((rowb >> 1) + 0) * 128 + col] = w0;
      cp[(size_t)((rowb >> 1) + 1) * 128 + col] = w1;
    }
  }
}

// ---------------- fused epi: sum partials -> upper write + mirrored lower write ------
// grid 36 tiles x 8 chunks = 288 blocks, 256 threads.
__global__ __launch_bounds__(256) void k_epi(const unsigned int* __restrict__ cpart,
                                             float* __restrict__ out, int S) {
  __shared__ float smir[16][132];
  const int b = (int)blockIdx.x;
  const int tile = b >> 3, chunk = b & 7;
  int rem = tile, ti = 0;
  while (rem >= 8 - ti) { rem -= 8 - ti; ++ti; }
  const int tj = ti + rem;
  const int t = (int)threadIdx.x;
  const int i4 = (b * 256 + t) * 4;
  const int rpl = t >> 5;             // rowpair-local 0..7
  const int c = (t & 31) * 4;

  const unsigned int* cp = cpart + i4;
  const size_t st = (size_t)NTILES * CP_U32;
  float lo0 = 0.f, lo1 = 0.f, lo2 = 0.f, lo3 = 0.f;
  float hi0 = 0.f, hi1 = 0.f, hi2 = 0.f, hi3 = 0.f;
  for (int s = 0; s < S; ++s) {
    const uint4 v = *(const uint4*)(cp + (size_t)s * st);
    lo0 += __uint_as_float(v.x << 16); hi0 += __uint_as_float(v.x & 0xFFFF0000u);
    lo1 += __uint_as_float(v.y << 16); hi1 += __uint_as_float(v.y & 0xFFFF0000u);
    lo2 += __uint_as_float(v.z << 16); hi2 += __uint_as_float(v.z & 0xFFFF0000u);
    lo3 += __uint_as_float(v.w << 16); hi3 += __uint_as_float(v.w & 0xFFFF0000u);
  }

  const float sc = 0.5f / (float)M_ROWS;
  f32x4 lo = (f32x4){lo0 * sc, lo1 * sc, lo2 * sc, lo3 * sc};
  f32x4 hi = (f32x4){hi0 * sc, hi1 * sc, hi2 * sc, hi3 * sc};

  const int gi = ti * 128 + chunk * 16 + 2 * rpl;
  const int gj = tj * 128 + c;
  if (ti == tj) {   // diag fixup: scaled - 0.5 on the diagonal
#pragma unroll
    for (int kk = 0; kk < 4; ++kk) {
      if (gi == gj + kk) lo[kk] -= 0.5f;
      if (gi + 1 == gj + kk) hi[kk] -= 0.5f;
    }
  }
  *(f32x4*)(out + (size_t)gi * D_DIM + gj) = lo;
  *(f32x4*)(out + (size_t)(gi + 1) * D_DIM + gj) = hi;

  if (ti != tj) {   // mirror lower block via LDS transpose
    const int jr = 2 * rpl;
    *(f32x4*)&smir[jr][c] = lo;
    *(f32x4*)&smir[jr + 1][c] = hi;
    __syncthreads();
    const int cc = t >> 1, j0 = (t & 1) * 8;
    f32x4 m0v, m1v;
    m0v[0] = smir[j0 + 0][cc]; m0v[1] = smir[j0 + 1][cc];
    m0v[2] = smir[j0 + 2][cc]; m0v[3] = smir[j0 + 3][cc];
    m1v[0] = smir[j0 + 4][cc]; m1v[1] = smir[j0 + 5][cc];
    m1v[2] = smir[j0 + 6][cc]; m1v[3] = smir[j0 + 7][cc];
    float* ob = out + (size_t)(tj * 128 + cc) * D_DIM + ti * 128 + chunk * 16 + j0;
    *(f32x4*)(ob + 0) = m0v;
    *(f32x4*)(ob + 4) = m1v;
  }
}

// ---------------- fin1: row stats reduce over 16 c-tiles + block partials ----------------
__global__ __launch_bounds__(256) void k_fin1(const float* __restrict__ rssp,
                                              const float* __restrict__ rs4p,
                                              float* __restrict__ scp) {
  __shared__ float sm[3][4];
  const int t = (int)threadIdx.x;
  const int m = (int)blockIdx.x * 256 + t;
  float a = 0.f, b = 0.f;
#pragma unroll
  for (int ct = 0; ct < 16; ++ct) {
    a += rssp[ct * M_ROWS + m];
    b += rs4p[ct * M_ROWS + m];
  }
  float corr = a * a - b;
#pragma unroll
  for (int off = 32; off; off >>= 1) {
    corr += __shfl_down(corr, off);
    a += __shfl_down(a, off);
    b += __shfl_down(b, off);
  }
  const int wv = t >> 6;
  if ((t & 63) == 0) { sm[0][wv] = corr; sm[1][wv] = a; sm[2][wv] = b; }
  __syncthreads();
  if (t == 0) {
    float c4 = 0.f, a4 = 0.f, b4 = 0.f;
#pragma unroll
    for (int i = 0; i < 4; ++i) { c4 += sm[0][i]; a4 += sm[1][i]; b4 += sm[2][i]; }
    scp[(int)blockIdx.x * 4 + 0] = c4;
    scp[(int)blockIdx.x * 4 + 1] = a4;
    scp[(int)blockIdx.x * 4 + 2] = b4;
  }
}

// ---------------- fin2: final scalars ----------------
__global__ __launch_bounds__(128) void k_fin2(const float* __restrict__ scp,
                                              float* __restrict__ out) {
  __shared__ float sm[3][2];
  const int t = (int)threadIdx.x;  // 0..127
  float c = scp[t * 4 + 0], a = scp[t * 4 + 1], b = scp[t * 4 + 2];
#pragma unroll
  for (int off = 32; off; off >>= 1) {
    c += __shfl_down(c, off);
    a += __shfl_down(a, off);
    b += __shfl_down(b, off);
  }
  const int wv = t >> 6;
  if ((t & 63) == 0) { sm[0][wv] = c; sm[1][wv] = a; sm[2][wv] = b; }
  __syncthreads();
  if (t == 0) {
    const double ct = (double)sm[0][0] + (double)sm[0][1];
    const double st = (double)sm[1][0] + (double)sm[1][1];
    const double qt = (double)sm[2][0] + (double)sm[2][1];
    const double N = (double)M_ROWS * (double)D_DIM;
    out[1048576] = (float)(ct / (double)M_ROWS / ((double)D_DIM * (double)D_DIM));
    out[1048577] = (float)((qt - 2.0 * st + N) / N);
  }
}

extern "C" void kernel_launch(void* const* d_in, const int* in_sizes, int n_in,
                              void* d_out, int out_size, void* d_ws, size_t ws_size,
                              hipStream_t stream) {
  (void)in_sizes; (void)n_in; (void)out_size;
  const float* x = (const float*)d_in[0];
  float* out = (float*)d_out;
  char* ws = (char*)d_ws;

  // ws layout:
  unsigned char* xt = (unsigned char*)ws;                   // 33,554,432 B (fp8, tiled)
  float* rssp = (float*)(ws + 33554432);                    //  2,097,152 B
  float* rs4p = (float*)(ws + 35651584);                    //  2,097,152 B
  float* scp  = (float*)(ws + 37748736);                    //      4,096 B
  unsigned int* cpart = (unsigned int*)(ws + 37752832);     //  S * 1,179,648 B
  const size_t base = 37752832;
  size_t avail = (ws_size > base) ? (ws_size - base) : 0;
  int S = (int)(avail / (sizeof(unsigned int) * NTILES * CP_U32));
  if (S > 32) S = 32;                 // 32 splits: 1152 blocks, 1MB L2 chunk/XCD
  int swz = 0;
  if (S >= 8) { S &= ~7; swz = 1; }   // multiple of 8 -> XCD-chunked decode
  if (S < 1) S = 1;

  k_pass1<<<8192, 256, 0, stream>>>(x, xt, rssp, rs4p);
  k_gemm<<<NTILES * S, 256, 0, stream>>>(xt, cpart, S, swz);
  k_epi<<<288, 256, 0, stream>>>(cpart, out, S);
  k_fin1<<<128, 256, 0, stream>>>(rssp, rs4p, scp);
  k_fin2<<<1, 128, 0, stream>>>(scp, out);
}

// Round 12
// 75.842 us; speedup vs baseline: 1.1630x; 1.0480x over previous
//
#include <hip/hip_runtime.h>
#include <hip/hip_bf16.h>
#include <stdint.h>
#include <stddef.h>

// DecorrLoss: grad = 0.5*mean_C(offdiag) + 0.5*diag(mean(x^2)-1), corr_loss, whit_loss
// x: f32 [8,4096,1024] -> [M=32768][D=1024]
//   pass1: f32 -> fp8 e4m3 (HW cvt_pk) TILE-LINEAR transposed XT (R11, verified)
//   gemm : 256x256 triangle tiles (10), 8 waves, MX-scaled fp8 MFMA 16x16x128,
//          split-K S=24 XCD-chunked, BK=128B, counted-vmcnt 2-deep pipeline
//          (vmcnt(8), raw s_barrier, stage-under-MFMA, setprio). bf16-packed C.
//   epi  : FUSED for 256^2 tiles: sum S partials -> upper write (+diag fixup) +
//          LDS-transposed mirror of the lower block.
//   fin1/fin2: deterministic scalar losses

#define D_DIM 1024
#define M_ROWS 32768
#define BK 128
#define NKBS (M_ROWS / BK)         // 256 K-blocks of 128
#define NT2 10                     // 4*5/2 triangle tiles at 256^2
#define CPT_U32 32768              // u32 per packed 256^2 tile
#define CT_STRIDE 2097152          // bytes per 64-row group in tiled xt

typedef __attribute__((ext_vector_type(4))) float f32x4;
typedef __attribute__((ext_vector_type(4))) int i32x4;
typedef __attribute__((ext_vector_type(8))) int i32x8;

__device__ inline unsigned short f2bf(float f) {
  unsigned int b = __float_as_uint(f);
  return (unsigned short)((b + 0x7fffu + ((b >> 16) & 1u)) >> 16);  // RNE
}

__device__ inline void gload_lds16(const void* g, void* l) {
  __builtin_amdgcn_global_load_lds(
      (const __attribute__((address_space(1))) void*)g,
      (__attribute__((address_space(3))) void*)l,
      16, 0, 0);
}

__device__ inline float dppsum16(float v) {
  v += __uint_as_float((unsigned)__builtin_amdgcn_update_dpp(
      0, (int)__float_as_uint(v), 0xB1, 0xF, 0xF, true));
  v += __uint_as_float((unsigned)__builtin_amdgcn_update_dpp(
      0, (int)__float_as_uint(v), 0x4E, 0xF, 0xF, true));
  v += __uint_as_float((unsigned)__builtin_amdgcn_update_dpp(
      0, (int)__float_as_uint(v), 0x141, 0xF, 0xF, true));
  v += __uint_as_float((unsigned)__builtin_amdgcn_update_dpp(
      0, (int)__float_as_uint(v), 0x140, 0xF, 0xF, true));
  return v;
}

// ---------------- pass 1 (R11, verified) ----------------
__global__ __launch_bounds__(256) void k_pass1(const float* __restrict__ x,
                                               unsigned char* __restrict__ xt,
                                               float* __restrict__ rssp,
                                               float* __restrict__ rs4p) {
  __shared__ unsigned int sh32[16 * 68];
  const int bid = blockIdx.x;
  const int mt = bid & 511;
  const int m0 = mt * 64;
  const int ct = bid >> 9;
  const int c0 = ct * 64;
  const int t = (int)threadIdx.x;
  const int q = t >> 4;
  const int cg = t & 15;

  unsigned int p[4];
  float ss[4], s4[4];
#pragma unroll
  for (int mi = 0; mi < 4; ++mi) {
    const float4 v = *(const float4*)(x + (size_t)(m0 + q * 4 + mi) * D_DIM + c0 + cg * 4);
    const float q0 = v.x * v.x, q1 = v.y * v.y, q2 = v.z * v.z, q3 = v.w * v.w;
    ss[mi] = q0 + q1 + q2 + q3;
    s4[mi] = q0 * q0 + q1 * q1 + q2 * q2 + q3 * q3;
    unsigned int u = (unsigned int)__builtin_amdgcn_cvt_pk_fp8_f32(v.x, v.y, 0, false);
    p[mi] = (unsigned int)__builtin_amdgcn_cvt_pk_fp8_f32(v.z, v.w, (int)u, true);
  }
#pragma unroll
  for (int mi = 0; mi < 4; ++mi) {
    ss[mi] = dppsum16(ss[mi]);
    s4[mi] = dppsum16(s4[mi]);
  }
  if (cg == 0) {
#pragma unroll
    for (int mi = 0; mi < 4; ++mi) {
      rssp[ct * M_ROWS + m0 + q * 4 + mi] = ss[mi];
      rs4p[ct * M_ROWS + m0 + q * 4 + mi] = s4[mi];
    }
  }

  const unsigned int t01l = __builtin_amdgcn_perm(p[1], p[0], 0x05010400u);
  const unsigned int t01h = __builtin_amdgcn_perm(p[1], p[0], 0x07030602u);
  const unsigned int t23l = __builtin_amdgcn_perm(p[3], p[2], 0x05010400u);
  const unsigned int t23h = __builtin_amdgcn_perm(p[3], p[2], 0x07030602u);
  uint4 w;
  w.x = __builtin_amdgcn_perm(t23l, t01l, 0x05040100u);
  w.y = __builtin_amdgcn_perm(t23l, t01l, 0x07060302u);
  w.z = __builtin_amdgcn_perm(t23h, t01h, 0x05040100u);
  w.w = __builtin_amdgcn_perm(t23h, t01h, 0x07060302u);
  *(uint4*)&sh32[q * 68 + cg * 4] = w;
  __syncthreads();

  const int c = t >> 2, mh = t & 3;
  uint4 o;
  o.x = sh32[(mh * 4 + 0) * 68 + c];
  o.y = sh32[(mh * 4 + 1) * 68 + c];
  o.z = sh32[(mh * 4 + 2) * 68 + c];
  o.w = sh32[(mh * 4 + 3) * 68 + c];
  *(uint4*)(xt + (size_t)ct * CT_STRIDE + ((size_t)mt << 12) + t * 16) = o;
}

// ---------------- gemm: 256^2 MX-fp8, counted-vmcnt 2-deep pipeline ----------------
// grid: S * 10 blocks, 512 threads (8 waves: 2M x 4N of 128x64)
// xt tile-linear: byte(row,k) = (row>>6)*CT_STRIDE + (k>>6)*4096 + (row&63)*64 + (k&63)
__global__ __launch_bounds__(512, 2) void k_gemm(const unsigned char* __restrict__ xt,
                                                 unsigned int* __restrict__ cpart,
                                                 int S, int swz) {
  __shared__ unsigned char As[2][32768];
  __shared__ unsigned char Bs[2][32768];
  const int bid = (int)blockIdx.x;
  int s, tidx;
  if (swz) {
    const int xcd = bid & 7;
    tidx = (bid >> 3) % NT2;
    s = (bid / (8 * NT2)) * 8 + xcd;
  } else {
    s = bid / NT2;
    tidx = bid - s * NT2;
  }
  int rem = tidx, ti = 0;
  while (rem >= 4 - ti) { rem -= 4 - ti; ++ti; }
  const int tj = ti + rem;

  const int t = (int)threadIdx.x;
  const int l = t & 63, w = t >> 6;
  const int wr2 = w >> 2, wc4 = w & 3;       // wave: rows wr2*128, cols wc4*64
  const int r = l & 15, g = l >> 4;

  f32x4 acc[8][4];
#pragma unroll
  for (int mi = 0; mi < 8; ++mi)
#pragma unroll
    for (int ni = 0; ni < 4; ++ni) acc[mi][ni] = (f32x4){0.f, 0.f, 0.f, 0.f};

  // staging: 512 threads cover 256 rows x 128B per matrix per buffer (4 x 16B each).
  // LDS dest [j*8192 + t*16] = row (j*64 + t>>3), slot (t&7); source slot ^ (row&7).
  const int srow = t >> 3;                   // 0..63
  const int slot = (t & 7) ^ (srow & 7);
  const int slterm = (slot >> 2) * 4096 + (slot & 3) * 16;
  const unsigned char* pa[4];
  const unsigned char* pb[4];
#pragma unroll
  for (int j = 0; j < 4; ++j) {
    pa[j] = xt + (size_t)(ti * 4 + j) * CT_STRIDE + srow * 64 + slterm;
    pb[j] = xt + (size_t)(tj * 4 + j) * CT_STRIDE + srow * 64 + slterm;
  }

  // diag tiles stage B redundantly (uniform 8 loads -> constant vmcnt counts)
#define STAGE(B, K) do { \
    const size_t koff = (size_t)(K) << 6; \
    _Pragma("unroll") \
    for (int j = 0; j < 4; ++j) { \
      gload_lds16(pa[j] + koff, &As[B][j * 8192 + t * 16]); \
      gload_lds16(pb[j] + koff, &Bs[B][j * 8192 + t * 16]); \
    } \
  } while (0)

  const int swb = r & 7;
  const int oA0 = (((2 * g + 0) ^ swb) << 4);
  const int oA1 = (((2 * g + 1) ^ swb) << 4);
  const int arow = (wr2 * 128 + r) * 128;
  const int brow = (wc4 * 64 + r) * 128;

  // K partition: NKBS chunks of BK over S splits
  const int kq = NKBS / S, kr = NKBS - kq * S;
  const int kb0 = s * kq + (s < kr ? s : kr);
  const int nkb = kq + (s < kr ? 1 : 0);
  int kb = kb0 * BK;

  STAGE(0, kb);
  STAGE(1, kb + BK);

  for (int it = 0; it < nkb; ++it) {
    if (it == nkb - 1)
      asm volatile("s_waitcnt vmcnt(0)" ::: "memory");
    else
      asm volatile("s_waitcnt vmcnt(8)" ::: "memory");
    __builtin_amdgcn_s_barrier();

    const unsigned char* Ab = As[it & 1];
    const unsigned char* Bb = Bs[it & 1];
    i32x8 a8[8], b8[4];
#pragma unroll
    for (int mi = 0; mi < 8; ++mi) {
      const i32x4 lo = *(const i32x4*)(Ab + arow + mi * 2048 + oA0);
      const i32x4 hi = *(const i32x4*)(Ab + arow + mi * 2048 + oA1);
      a8[mi] = (i32x8){lo[0], lo[1], lo[2], lo[3], hi[0], hi[1], hi[2], hi[3]};
    }
#pragma unroll
    for (int ni = 0; ni < 4; ++ni) {
      const i32x4 lo = *(const i32x4*)(Bb + brow + ni * 2048 + oA0);
      const i32x4 hi = *(const i32x4*)(Bb + brow + ni * 2048 + oA1);
      b8[ni] = (i32x8){lo[0], lo[1], lo[2], lo[3], hi[0], hi[1], hi[2], hi[3]};
    }
    asm volatile("s_waitcnt lgkmcnt(0)" ::: "memory");
    __builtin_amdgcn_s_barrier();

    if (it + 2 < nkb) STAGE(it & 1, kb + 2 * BK);  // flight hides under MFMAs

    __builtin_amdgcn_s_setprio(1);
#pragma unroll
    for (int ni = 0; ni < 4; ++ni)
#pragma unroll
      for (int mi = 0; mi < 8; ++mi)
        acc[mi][ni] = __builtin_amdgcn_mfma_scale_f32_16x16x128_f8f6f4(
            a8[mi], b8[ni], acc[mi][ni], 0, 0, 0, 0x7F7F7F7Fu, 0, 0x7F7F7F7Fu);
    __builtin_amdgcn_s_setprio(0);
    kb += BK;
  }
#undef STAGE

  // C/D: col = lane&15, row = (lane>>4)*4 + reg. Pack row-pairs as bf16.
  unsigned int* cp = cpart + ((size_t)s * NT2 + tidx) * CPT_U32;
#pragma unroll
  for (int mi = 0; mi < 8; ++mi) {
    const int rowb = wr2 * 128 + mi * 16 + g * 4;   // even
#pragma unroll
    for (int ni = 0; ni < 4; ++ni) {
      const int col = wc4 * 64 + ni * 16 + r;
      const unsigned int w0 = (unsigned int)f2bf(acc[mi][ni][0]) |
                              ((unsigned int)f2bf(acc[mi][ni][1]) << 16);
      const unsigned int w1 = (unsigned int)f2bf(acc[mi][ni][2]) |
                              ((unsigned int)f2bf(acc[mi][ni][3]) << 16);
      cp[(size_t)((rowb >> 1) + 0) * 256 + col] = w0;
      cp[(size_t)((rowb >> 1) + 1) * 256 + col] = w1;
    }
  }
}

// ---------------- fused epi for 256^2 tiles ----------------
// grid 10 tiles x 32 chunks = 320 blocks, 256 threads.
// thread: rowpair rp = chunk*4 + (t>>6), cols c..c+3 with c = 4*(t&63).
__global__ __launch_bounds__(256) void k_epi(const unsigned int* __restrict__ cpart,
                                             float* __restrict__ out, int S) {
  __shared__ float smir[8][260];
  const int b = (int)blockIdx.x;
  const int tile = b >> 5, chunk = b & 31;
  int rem = tile, ti = 0;
  while (rem >= 4 - ti) { rem -= 4 - ti; ++ti; }
  const int tj = ti + rem;
  const int t = (int)threadIdx.x;
  const int qq = (chunk * 256 + t) * 4;   // u32 index within tile
  const int rpl = t >> 6;                 // rowpair-local 0..3
  const int c = (t & 63) * 4;

  const unsigned int* cp = cpart + (size_t)tile * CPT_U32 + qq;
  const size_t st = (size_t)NT2 * CPT_U32;
  float lo0 = 0.f, lo1 = 0.f, lo2 = 0.f, lo3 = 0.f;
  float hi0 = 0.f, hi1 = 0.f, hi2 = 0.f, hi3 = 0.f;
  for (int s = 0; s < S; ++s) {
    const uint4 v = *(const uint4*)(cp + (size_t)s * st);
    lo0 += __uint_as_float(v.x << 16); hi0 += __uint_as_float(v.x & 0xFFFF0000u);
    lo1 += __uint_as_float(v.y << 16); hi1 += __uint_as_float(v.y & 0xFFFF0000u);
    lo2 += __uint_as_float(v.z << 16); hi2 += __uint_as_float(v.z & 0xFFFF0000u);
    lo3 += __uint_as_float(v.w << 16); hi3 += __uint_as_float(v.w & 0xFFFF0000u);
  }

  const float sc = 0.5f / (float)M_ROWS;
  f32x4 lo = (f32x4){lo0 * sc, lo1 * sc, lo2 * sc, lo3 * sc};
  f32x4 hi = (f32x4){hi0 * sc, hi1 * sc, hi2 * sc, hi3 * sc};

  const int gi = ti * 256 + chunk * 8 + 2 * rpl;
  const int gj = tj * 256 + c;
  if (ti == tj) {   // diag fixup
#pragma unroll
    for (int kk = 0; kk < 4; ++kk) {
      if (gi == gj + kk) lo[kk] -= 0.5f;
      if (gi + 1 == gj + kk) hi[kk] -= 0.5f;
    }
  }
  *(f32x4*)(out + (size_t)gi * D_DIM + gj) = lo;
  *(f32x4*)(out + (size_t)(gi + 1) * D_DIM + gj) = hi;

  if (ti != tj) {   // mirror lower block via LDS transpose
    const int jr = 2 * rpl;
    *(f32x4*)&smir[jr][c] = lo;
    *(f32x4*)&smir[jr + 1][c] = hi;
    __syncthreads();
    const int cc = t;                      // 0..255
    f32x4 m0v, m1v;
    m0v[0] = smir[0][cc]; m0v[1] = smir[1][cc];
    m0v[2] = smir[2][cc]; m0v[3] = smir[3][cc];
    m1v[0] = smir[4][cc]; m1v[1] = smir[5][cc];
    m1v[2] = smir[6][cc]; m1v[3] = smir[7][cc];
    float* ob = out + (size_t)(tj * 256 + cc) * D_DIM + ti * 256 + chunk * 8;
    *(f32x4*)(ob + 0) = m0v;
    *(f32x4*)(ob + 4) = m1v;
  }
}

// ---------------- fin1 / fin2 (unchanged) ----------------
__global__ __launch_bounds__(256) void k_fin1(const float* __restrict__ rssp,
                                              const float* __restrict__ rs4p,
                                              float* __restrict__ scp) {
  __shared__ float sm[3][4];
  const int t = (int)threadIdx.x;
  const int m = (int)blockIdx.x * 256 + t;
  float a = 0.f, b = 0.f;
#pragma unroll
  for (int ct = 0; ct < 16; ++ct) {
    a += rssp[ct * M_ROWS + m];
    b += rs4p[ct * M_ROWS + m];
  }
  float corr = a * a - b;
#pragma unroll
  for (int off = 32; off; off >>= 1) {
    corr += __shfl_down(corr, off);
    a += __shfl_down(a, off);
    b += __shfl_down(b, off);
  }
  const int wv = t >> 6;
  if ((t & 63) == 0) { sm[0][wv] = corr; sm[1][wv] = a; sm[2][wv] = b; }
  __syncthreads();
  if (t == 0) {
    float c4 = 0.f, a4 = 0.f, b4 = 0.f;
#pragma unroll
    for (int i = 0; i < 4; ++i) { c4 += sm[0][i]; a4 += sm[1][i]; b4 += sm[2][i]; }
    scp[(int)blockIdx.x * 4 + 0] = c4;
    scp[(int)blockIdx.x * 4 + 1] = a4;
    scp[(int)blockIdx.x * 4 + 2] = b4;
  }
}

__global__ __launch_bounds__(128) void k_fin2(const float* __restrict__ scp,
                                              float* __restrict__ out) {
  __shared__ float sm[3][2];
  const int t = (int)threadIdx.x;
  float c = scp[t * 4 + 0], a = scp[t * 4 + 1], b = scp[t * 4 + 2];
#pragma unroll
  for (int off = 32; off; off >>= 1) {
    c += __shfl_down(c, off);
    a += __shfl_down(a, off);
    b += __shfl_down(b, off);
  }
  const int wv = t >> 6;
  if ((t & 63) == 0) { sm[0][wv] = c; sm[1][wv] = a; sm[2][wv] = b; }
  __syncthreads();
  if (t == 0) {
    const double ct = (double)sm[0][0] + (double)sm[0][1];
    const double st = (double)sm[1][0] + (double)sm[1][1];
    const double qt = (double)sm[2][0] + (double)sm[2][1];
    const double N = (double)M_ROWS * (double)D_DIM;
    out[1048576] = (float)(ct / (double)M_ROWS / ((double)D_DIM * (double)D_DIM));
    out[1048577] = (float)((qt - 2.0 * st + N) / N);
  }
}

extern "C" void kernel_launch(void* const* d_in, const int* in_sizes, int n_in,
                              void* d_out, int out_size, void* d_ws, size_t ws_size,
                              hipStream_t stream) {
  (void)in_sizes; (void)n_in; (void)out_size;
  const float* x = (const float*)d_in[0];
  float* out = (float*)d_out;
  char* ws = (char*)d_ws;

  // ws layout:
  unsigned char* xt = (unsigned char*)ws;                   // 33,554,432 B (fp8, tiled)
  float* rssp = (float*)(ws + 33554432);                    //  2,097,152 B
  float* rs4p = (float*)(ws + 35651584);                    //  2,097,152 B
  float* scp  = (float*)(ws + 37748736);                    //      4,096 B
  unsigned int* cpart = (unsigned int*)(ws + 37752832);     //  S * 1,310,720 B
  const size_t base = 37752832;
  size_t avail = (ws_size > base) ? (ws_size - base) : 0;
  int S = (int)(avail / (sizeof(unsigned int) * NT2 * CPT_U32));
  if (S > 24) S = 24;                 // 240 blocks ~ 1/CU (LDS 128KB), XCD-chunked
  int swz = 0;
  if (S >= 8) { S &= ~7; swz = 1; }
  if (S < 1) S = 1;

  k_pass1<<<8192, 256, 0, stream>>>(x, xt, rssp, rs4p);
  k_gemm<<<NT2 * S, 512, 0, stream>>>(xt, cpart, S, swz);
  k_epi<<<NT2 * 32, 256, 0, stream>>>(cpart, out, S);
  k_fin1<<<128, 256, 0, stream>>>(rssp, rs4p, scp);
  k_fin2<<<1, 128, 0, stream>>>(scp, out);
}